// Round 7
// baseline (225.384 us; speedup 1.0000x reference)
//
#include <hip/hip_runtime.h>
#include <hip/hip_bf16.h>

#define NB   32
#define CIN  128
#define COUT 256
#define HH   56
#define WW   56

typedef __attribute__((ext_vector_type(8))) short short8;   // 8 bf16 (4 VGPRs)
typedef __attribute__((ext_vector_type(4))) float f32x4;    // MFMA accumulator

// round-to-nearest-even fp32 -> bf16 (raw u16)
__device__ __forceinline__ unsigned short f2bf(float f) {
    unsigned int u = __builtin_bit_cast(unsigned int, f);
    u = u + 0x7fffu + ((u >> 16) & 1u);
    return (unsigned short)(u >> 16);
}

// ---------------------------------------------------------------------------
// Pre-pass: weights OIHW f32 -> wt2 in EXACT MFMA A-fragment order:
//   wt2[((s*16 + f)*64 + lane)*8 + j]
//   s = K-step (t = s>>2 tap, cc = s&3 channel-quad), f = 16-row M-fragment,
//   lane: g = lane>>4 (k-subgroup), r = lane&15 (row within fragment),
//   element = w[o = f*16 + r][c = cc*32 + g*8 + j][tap t]
// A wave's per-step fragment load is ONE coalesced global_load_dwordx4,
// L1/L2-resident (576 KB total, identical stream for every block).
// ---------------------------------------------------------------------------
__global__ __launch_bounds__(256) void wpose_kernel(const float* __restrict__ w,
                                                    unsigned short* __restrict__ wt2) {
    int q = blockIdx.x * 256 + threadIdx.x;    // element index
    if (q >= 36 * 16 * 64 * 8) return;
    int j = q & 7;
    int l = (q >> 3) & 63;
    int f = (q >> 9) & 15;
    int s = q >> 13;
    int g = l >> 4, r = l & 15;
    int t = s >> 2, cc = s & 3;
    int o = f * 16 + r;
    int c = cc * 32 + g * 8 + j;
    wt2[q] = f2bf(w[((size_t)o * CIN + c) * 9 + t]);
}

// ---------------------------------------------------------------------------
// Main conv: block = 256 Cout x 224 spatial (4 output rows h0..h0+3),
// 1024 threads = 16 waves as 2(M) x 8(N).
// Wave tile = 128 Cout (8 M-frags) x 32 cols (2 N-frags); block N padded to
// 256 cols, the last 32 masked at store. LDS B-read traffic per K-step =
// M_waves(2) x 16 col-frags x 1KB = 32 KB  (round 6 was 112 KB -> LDS-port
// bound at MfmaUtil 30%). Now LDS ~13.6k cyc vs MFMA ~11.2k cyc per block.
//   A: direct global frag loads from wt2 (8/wave/step; L1-shared by N-waves).
//   B: x rows h0-1..h0+4 transposed in-block NCHW f32 -> bf16 LDS:
//      ldsB[((row*16 + gc)*58 + wpos)*8], wpos 0/57 + OOB rows = zero pads.
//      Channel-major lane mapping on the transpose writes (~4-way conflicts).
// K-loop ds_read addressing: per-thread base VGPR + 16-bit imm offset
// (kh*928 + cc*232 + kw chunks, max 40864 B < 65536).
// ---------------------------------------------------------------------------
__global__ __launch_bounds__(1024, 4) void conv_mfma_kernel(
        const float* __restrict__ x,
        const unsigned short* __restrict__ wt2,
        const float* __restrict__ bias,
        float* __restrict__ out) {
    __shared__ unsigned short ldsB[6 * 16 * 58 * 8];    // 89088 B

    const int tid  = threadIdx.x;
    const int h0   = blockIdx.x * 4, n = blockIdx.y;
    const int wid  = tid >> 6, lane = tid & 63;
    const int wm   = wid >> 3, wn = wid & 7;            // 2M x 8N wave grid
    const int g    = lane >> 4, r = lane & 15;

    // ---- zero all 5568 chunks (pads + OOB rows stay zero) ----
    for (int i = tid; i < 6 * 16 * 58; i += 1024) {
        uint4 z = {0u, 0u, 0u, 0u};
        *(uint4*)&ldsB[(size_t)i * 8] = z;
    }
    __syncthreads();

    // ---- fused transpose: channel-major lanes, scalar f32 reads (L1-hot),
    //      packed dword writes (~4-way bank alias) ----
    {
        const float* xn = x + (size_t)n * CIN * HH * WW;
        const int cp = tid & 63, e = cp & 3, gcq = cp >> 2;
        const float* pc = xn + (size_t)(2 * cp) * (HH * WW);
        for (int rw = tid >> 6; rw < 6 * 56; rw += 16) {
            int row = rw / 56, w = rw - row * 56;
            int hs  = h0 + row - 1;
            if ((unsigned)hs < HH) {
                const float* p = pc + hs * WW + w;
                unsigned int pk = (unsigned int)f2bf(p[0])
                                | ((unsigned int)f2bf(p[HH * WW]) << 16);
                ((unsigned int*)ldsB)[((row * 16 + gcq) * 58 + (w + 1)) * 4 + e] = pk;
            }
        }
    }
    __syncthreads();    // B ready; no more barriers

    // per-lane N-frag geometry: c = wn*32 + ni*16 + r  (c >= 224 masked)
    int hrv[2], wv[2], base2[2];
    bool ok[2];
    #pragma unroll
    for (int ni = 0; ni < 2; ++ni) {
        int c = wn * 32 + ni * 16 + r;
        ok[ni] = (c < 224);
        int hr, w;
        if (ok[ni]) { hr = c / 56; w = c - hr * 56; }
        else        { hr = 3;      w = c & 31; }       // safe dummy reads
        hrv[ni] = hr; wv[ni] = w;
        base2[ni] = hr * 928 + g * 58 + w;             // chunk base (x16 B)
    }

    f32x4 acc[8][2];
    #pragma unroll
    for (int mi = 0; mi < 8; ++mi)
        #pragma unroll
        for (int ni = 0; ni < 2; ++ni)
            #pragma unroll
            for (int v = 0; v < 4; ++v) acc[mi][ni][v] = 0.f;

    // wave's A base: fragment f = wm*8 + mi, chunk ((s*16+f)*64 + lane)
    const short8* abase = (const short8*)wt2 + (size_t)(wm * 8) * 64 + lane;

    #pragma unroll
    for (int t = 0; t < 9; ++t) {
        const int kh = t / 3, kw = t % 3;
        #pragma unroll
        for (int cc = 0; cc < 4; ++cc) {
            const int s = t * 4 + cc;

            short8 a[8];
            #pragma unroll
            for (int mi = 0; mi < 8; ++mi)
                a[mi] = abase[(size_t)s * 1024 + mi * 64];

            const int koff = kh * 928 + cc * 232 + kw;  // imm chunk offset
            short8 b[2];
            #pragma unroll
            for (int ni = 0; ni < 2; ++ni)
                b[ni] = *(const short8*)&ldsB[(size_t)(base2[ni] + koff) * 8];

            #pragma unroll
            for (int mi = 0; mi < 8; ++mi)
                #pragma unroll
                for (int ni = 0; ni < 2; ++ni)
                    acc[mi][ni] = __builtin_amdgcn_mfma_f32_16x16x32_bf16(
                        a[mi], b[ni], acc[mi][ni], 0, 0, 0);
        }
    }

    // ---- epilogue: D col = r (spatial), row = g*4+v (Cout within frag) ----
    #pragma unroll
    for (int mi = 0; mi < 8; ++mi) {
        const int o0 = wm * 128 + mi * 16 + 4 * g;
        const float4 bv = *(const float4*)&bias[o0];
        #pragma unroll
        for (int ni = 0; ni < 2; ++ni) {
            if (ok[ni]) {
                const int h = h0 + hrv[ni];
                const int w = wv[ni];
                #pragma unroll
                for (int v = 0; v < 4; ++v) {
                    out[((size_t)(n * COUT + o0 + v) * HH + h) * WW + w] =
                        acc[mi][ni][v] + ((const float*)&bv)[v];
                }
            }
        }
    }
}

extern "C" void kernel_launch(void* const* d_in, const int* in_sizes, int n_in,
                              void* d_out, int out_size, void* d_ws, size_t ws_size,
                              hipStream_t stream) {
    const float* x  = (const float*)d_in[0];   // (32,128,56,56)
    const float* wk = (const float*)d_in[1];   // (256,128,3,3)
    const float* b  = (const float*)d_in[2];   // (256,)
    float* out = (float*)d_out;

    unsigned short* wt2 = (unsigned short*)d_ws;   // 294,912 elems = 590 KB

    wpose_kernel<<<(36 * 16 * 64 * 8 + 255) / 256, 256, 0, stream>>>(wk, wt2);
    dim3 gc(14, NB);
    conv_mfma_kernel<<<gc, 1024, 0, stream>>>(x, wt2, b, out);
    (void)ws_size; (void)in_sizes; (void)n_in; (void)out_size;
}

// Round 8
// 119.669 us; speedup vs baseline: 1.8834x; 1.8834x over previous
//
#include <hip/hip_runtime.h>
#include <hip/hip_bf16.h>

#define NB   32
#define CIN  128
#define COUT 256
#define HH   56
#define WW   56

typedef __attribute__((ext_vector_type(8))) short short8;   // 8 bf16 (4 VGPRs)
typedef __attribute__((ext_vector_type(4))) float f32x4;    // MFMA accumulator

// round-to-nearest-even fp32 -> bf16 (raw u16)
__device__ __forceinline__ unsigned short f2bf(float f) {
    unsigned int u = __builtin_bit_cast(unsigned int, f);
    u = u + 0x7fffu + ((u >> 16) & 1u);
    return (unsigned short)(u >> 16);
}

// async global->LDS, 16B per lane; LDS dest = wave-uniform base + lane*16
__device__ __forceinline__ void glds16(const unsigned short* g, unsigned short* l) {
    __builtin_amdgcn_global_load_lds(
        (const __attribute__((address_space(1))) unsigned int*)g,
        (__attribute__((address_space(3))) unsigned int*)l,
        16, 0, 0);
}

// ---------------------------------------------------------------------------
// Pre-pass: weights OIHW f32 -> wt2 in MFMA A-fragment order:
//   chunk q/8: ((s*16 + f)*64 + lane), elem j = q&7
//   s = K-step (t=s>>2 tap, cc=s&3 chan-quad), f = M-fragment, lane=(g,r)
//   element = w[o = f*16 + r][c = cc*32 + g*8 + j][tap t]
// Per K-step slice s: 16 KB contiguous -> perfect global_load_lds source.
// ---------------------------------------------------------------------------
__global__ __launch_bounds__(256) void wpose_kernel(const float* __restrict__ w,
                                                    unsigned short* __restrict__ wt2) {
    int q = blockIdx.x * 256 + threadIdx.x;    // element index
    if (q >= 36 * 16 * 64 * 8) return;
    int j = q & 7;
    int l = (q >> 3) & 63;
    int f = (q >> 9) & 15;
    int s = q >> 13;
    int g = l >> 4, r = l & 15;
    int t = s >> 2, cc = s & 3;
    int o = f * 16 + r;
    int c = cc * 32 + g * 8 + j;
    wt2[q] = f2bf(w[((size_t)o * CIN + c) * 9 + t]);
}

// ---------------------------------------------------------------------------
// Main conv: block = 256 Cout x 224 spatial (4 output rows h0..h0+3),
// 512 threads = 8 waves as 4(M) x 2(N); wave = 64 Cout x 112 cols
// (4 M-frags x 7 N-frags, zero padding waste). K = 36 steps of 32.
//   A: per-step 16 KB slice of wt2 staged into double-buffered LDS via
//      global_load_lds (ONE copy per block per step -> L1 port off the
//      critical path; waves frag-read from LDS at ~256 B/cyc).
//   B: x rows h0-1..h0+4 transposed in-block NCHW f32 -> bf16 LDS once:
//      ldsB[((row*16 + gc)*58 + wpos)*8], wpos 0/57 + OOB rows = zero pads.
// Per step per CU: MFMA ~900 cyc  vs  LDS-read 88 KB ~344 cyc -> MFMA-bound.
// One __syncthreads per step (drains this step's A-prefetch into buf^1).
// ---------------------------------------------------------------------------
__global__ __launch_bounds__(512, 2) void conv_mfma_kernel(
        const float* __restrict__ x,
        const unsigned short* __restrict__ wt2,
        const float* __restrict__ bias,
        float* __restrict__ out) {
    __shared__ unsigned short ldsB[6 * 16 * 58 * 8];     // 89088 B
    __shared__ unsigned short ldsA[2][16 * 64 * 8];      // 2 x 16384 B

    const int tid  = threadIdx.x;
    const int h0   = blockIdx.x * 4, n = blockIdx.y;
    const int wid  = tid >> 6, lane = tid & 63;
    const int wm   = wid >> 1, wn = wid & 1;             // 4M x 2N wave grid
    const int g    = lane >> 4, r = lane & 15;

    // ---- zero B chunks (pads + OOB rows stay zero) ----
    for (int i = tid; i < 6 * 16 * 58; i += 512) {
        uint4 z = {0u, 0u, 0u, 0u};
        *(uint4*)&ldsB[(size_t)i * 8] = z;
    }
    __syncthreads();

    // ---- fused transpose: channel-major lanes (lane = channel-pair),
    //      scalar f32 reads (L1-hot after first touch), packed dword writes ----
    {
        const float* xn = x + (size_t)n * CIN * HH * WW;
        const int cp = lane, e = cp & 3, gcq = cp >> 2;
        const float* pc = xn + (size_t)(2 * cp) * (HH * WW);
        for (int rw = wid; rw < 6 * 56; rw += 8) {
            int row = rw / 56, w = rw - row * 56;
            int hs  = h0 + row - 1;
            if ((unsigned)hs < HH) {
                const float* p = pc + hs * WW + w;
                unsigned int pk = (unsigned int)f2bf(p[0])
                                | ((unsigned int)f2bf(p[HH * WW]) << 16);
                ((unsigned int*)ldsB)[((row * 16 + gcq) * 58 + (w + 1)) * 4 + e] = pk;
            }
        }
    }

    // ---- A stage: step s slice = wt2 + s*16KB, 1024 chunks; wave w loads
    //      chunks w*64+lane and 512+w*64+lane (wave-uniform LDS dests) ----
    #define STAGE_A(buf, s)                                                     \
        {                                                                       \
            const unsigned short* asrc = wt2 + (size_t)(s) * (16 * 64 * 8);     \
            glds16(asrc + (size_t)(wid * 64 + lane) * 8,                        \
                   &ldsA[buf][(size_t)(wid * 64) * 8]);                         \
            glds16(asrc + (size_t)(512 + wid * 64 + lane) * 8,                  \
                   &ldsA[buf][(size_t)(512 + wid * 64) * 8]);                   \
        }

    STAGE_A(0, 0);
    __syncthreads();    // B transpose writes + first A slice drained

    // per-lane chunk offsets for the 7 N-fragments (col c = ni*16 + r within
    // this wave's 112-col half; row-split handled via +928 chunks = 16*58)
    int lo[7];
    #pragma unroll
    for (int ni = 0; ni < 7; ++ni) {
        int c  = ni * 16 + r;
        int hr = (c >= 56) ? 1 : 0;
        lo[ni] = hr * (16 * 58) + (c - hr * 56);
    }

    f32x4 acc[4][7];
    #pragma unroll
    for (int mi = 0; mi < 4; ++mi)
        #pragma unroll
        for (int ni = 0; ni < 7; ++ni)
            #pragma unroll
            for (int v = 0; v < 4; ++v) acc[mi][ni][v] = 0.f;

    int cur = 0;
    #pragma unroll 1
    for (int s = 0; s < 36; ++s) {
        if (s < 35) STAGE_A(cur ^ 1, s + 1);

        const int t  = s >> 2, cc = s & 3;
        const int kh = t / 3, kw = t - 3 * (t / 3);
        const int gc = cc * 4 + g;
        const int bb = (((wn * 2 + kh) * 16 + gc) * 58 + kw);

        // A frags from LDS: chunk (f*64 + lane), f = wm*4 + mi
        short8 a[4];
        #pragma unroll
        for (int mi = 0; mi < 4; ++mi)
            a[mi] = *(const short8*)&ldsA[cur][(size_t)(((wm * 4 + mi) * 64 + lane)) * 8];

        short8 b[7];
        #pragma unroll
        for (int ni = 0; ni < 7; ++ni)
            b[ni] = *(const short8*)&ldsB[(size_t)(bb + lo[ni]) * 8];

        #pragma unroll
        for (int mi = 0; mi < 4; ++mi)
            #pragma unroll
            for (int ni = 0; ni < 7; ++ni)
                acc[mi][ni] = __builtin_amdgcn_mfma_f32_16x16x32_bf16(
                    a[mi], b[ni], acc[mi][ni], 0, 0, 0);

        __syncthreads();    // drains this step's A prefetch; buf^1 ready
        cur ^= 1;
    }

    // ---- epilogue: D col = r (spatial), row = g*4+v (Cout within frag) ----
    #pragma unroll
    for (int mi = 0; mi < 4; ++mi) {
        const int o0 = wm * 64 + mi * 16 + 4 * g;
        const float4 bv = *(const float4*)&bias[o0];
        #pragma unroll
        for (int ni = 0; ni < 7; ++ni) {
            const int c  = ni * 16 + r;
            const int hr = (c >= 56) ? 1 : 0;
            const int h  = h0 + wn * 2 + hr;
            const int w  = c - hr * 56;
            #pragma unroll
            for (int v = 0; v < 4; ++v) {
                out[((size_t)(n * COUT + o0 + v) * HH + h) * WW + w] =
                    acc[mi][ni][v] + ((const float*)&bv)[v];
            }
        }
    }
}

extern "C" void kernel_launch(void* const* d_in, const int* in_sizes, int n_in,
                              void* d_out, int out_size, void* d_ws, size_t ws_size,
                              hipStream_t stream) {
    const float* x  = (const float*)d_in[0];   // (32,128,56,56)
    const float* wk = (const float*)d_in[1];   // (256,128,3,3)
    const float* b  = (const float*)d_in[2];   // (256,)
    float* out = (float*)d_out;

    unsigned short* wt2 = (unsigned short*)d_ws;   // 294,912 elems = 590 KB

    wpose_kernel<<<(36 * 16 * 64 * 8 + 255) / 256, 256, 0, stream>>>(wk, wt2);
    dim3 gc(14, NB);
    conv_mfma_kernel<<<gc, 512, 0, stream>>>(x, wt2, b, out);
    (void)ws_size; (void)in_sizes; (void)n_in; (void)out_size;
}

// Round 9
// 111.942 us; speedup vs baseline: 2.0134x; 1.0690x over previous
//
#include <hip/hip_runtime.h>
#include <hip/hip_bf16.h>

#define NB   32
#define CIN  128
#define COUT 256
#define HH   56
#define WW   56

typedef __attribute__((ext_vector_type(8))) short short8;   // 8 bf16 (4 VGPRs)
typedef __attribute__((ext_vector_type(4))) float f32x4;    // MFMA accumulator

// round-to-nearest-even fp32 -> bf16 (raw u16)
__device__ __forceinline__ unsigned short f2bf(float f) {
    unsigned int u = __builtin_bit_cast(unsigned int, f);
    u = u + 0x7fffu + ((u >> 16) & 1u);
    return (unsigned short)(u >> 16);
}

// async global->LDS, 16B per lane; LDS dest = wave-uniform base + lane*16
__device__ __forceinline__ void glds16(const unsigned short* g, unsigned short* l) {
    __builtin_amdgcn_global_load_lds(
        (const __attribute__((address_space(1))) unsigned int*)g,
        (__attribute__((address_space(3))) unsigned int*)l,
        16, 0, 0);
}

// ---------------------------------------------------------------------------
// Pre-pass: weights OIHW f32 -> wt2 in MFMA A-fragment order:
//   chunk q/8: ((s*16 + f)*64 + lane), elem j = q&7
//   s = K-step (t=s>>2 tap, cc=s&3 chan-quad), f = M-fragment, lane=(g,r)
//   element = w[o = f*16 + r][c = cc*32 + g*8 + j][tap t]
// Per K-step slice s: 16 KB contiguous -> perfect global_load_lds source.
// ---------------------------------------------------------------------------
__global__ __launch_bounds__(256) void wpose_kernel(const float* __restrict__ w,
                                                    unsigned short* __restrict__ wt2) {
    int q = blockIdx.x * 256 + threadIdx.x;    // element index
    if (q >= 36 * 16 * 64 * 8) return;
    int j = q & 7;
    int l = (q >> 3) & 63;
    int f = (q >> 9) & 15;
    int s = q >> 13;
    int g = l >> 4, r = l & 15;
    int t = s >> 2, cc = s & 3;
    int o = f * 16 + r;
    int c = cc * 32 + g * 8 + j;
    wt2[q] = f2bf(w[((size_t)o * CIN + c) * 9 + t]);
}

// ---------------------------------------------------------------------------
// Main conv: block = 256 Cout x 224 spatial (4 output rows h0..h0+3),
// 512 threads = 8 waves as 4(M) x 2(N); wave = 64 Cout x 112 cols
// (4 M-frags x 7 N-frags of 16x16x32; zero N-padding waste). 36 K-steps.
//
// A pipeline (T3/T4 port): ring of 4 x 16KB LDS slices, prefetch distance 3,
// counted `s_waitcnt vmcnt(4)` + RAW s_barrier per step (never vmcnt(0) ->
// slices s+1,s+2 stay in flight across barriers). Ring-4 race-free: step s
// writes slot (s+3)&3 = (s-1)&3, whose readers finished before barrier(s).
// B: x rows h0-1..h0+4 transposed in-block (NCHW f32 -> bf16) ONCE:
//   ldsB[((row*16 + gc)*58 + wpos)*8]; wpos 0/57 + OOB rows = zero pads.
// Per step per CU: MFMA ~1086 cyc vs LDS-read (A 32KB + B 56KB) ~344 cyc
// -> MFMA-bound; glds latency hidden across 3 steps.
// ---------------------------------------------------------------------------
__global__ __launch_bounds__(512, 2) void conv_mfma_kernel(
        const float* __restrict__ x,
        const unsigned short* __restrict__ wt2,
        const float* __restrict__ bias,
        float* __restrict__ out) {
    __shared__ unsigned short ldsB[6 * 16 * 58 * 8];     // 89088 B
    __shared__ unsigned short ldsA[4][16 * 64 * 8];      // 4 x 16384 B

    const int tid  = threadIdx.x;
    const int h0   = blockIdx.x * 4, n = blockIdx.y;
    const int wid  = tid >> 6, lane = tid & 63;
    const int wm   = wid >> 1, wn = wid & 1;             // 4M x 2N wave grid
    const int g    = lane >> 4, r = lane & 15;

    // ---- zero B chunks (pads + OOB rows stay zero) ----
    for (int i = tid; i < 6 * 16 * 58; i += 512) {
        uint4 z = {0u, 0u, 0u, 0u};
        *(uint4*)&ldsB[(size_t)i * 8] = z;
    }
    __syncthreads();

    // ---- fused transpose: channel-major lanes (lane = channel-pair),
    //      scalar f32 reads (L1-hot after first touch), packed dword writes ----
    {
        const float* xn = x + (size_t)n * CIN * HH * WW;
        const int cp = lane, e = cp & 3, gcq = cp >> 2;
        const float* pc = xn + (size_t)(2 * cp) * (HH * WW);
        for (int rw = wid; rw < 6 * 56; rw += 8) {
            int row = rw / 56, w = rw - row * 56;
            int hs  = h0 + row - 1;
            if ((unsigned)hs < HH) {
                const float* p = pc + hs * WW + w;
                unsigned int pk = (unsigned int)f2bf(p[0])
                                | ((unsigned int)f2bf(p[HH * WW]) << 16);
                ((unsigned int*)ldsB)[((row * 16 + gcq) * 58 + (w + 1)) * 4 + e] = pk;
            }
        }
    }
    __syncthreads();    // B ready; all prior vmem consumed -> vmcnt clean

    // ---- A stage: slice s -> ring slot; wave wid loads frag rows f=wid and
    //      f=8+wid (wave-uniform LDS dests, per-lane global srcs) ----
    #define STAGE_A(slot, s)                                                    \
        {                                                                       \
            const unsigned short* asrc = wt2 + (size_t)(s) * (16 * 64 * 8);     \
            glds16(asrc + (size_t)(wid * 64 + lane) * 8,                        \
                   &ldsA[slot][(size_t)(wid * 64) * 8]);                        \
            glds16(asrc + (size_t)((8 + wid) * 64 + lane) * 8,                  \
                   &ldsA[slot][(size_t)((8 + wid) * 64) * 8]);                  \
        }

    STAGE_A(0, 0);
    STAGE_A(1, 1);
    STAGE_A(2, 2);      // 6 loads in flight per wave

    // per-lane chunk offsets for the 7 N-fragments (col c = ni*16 + r within
    // this wave's 112-col half; row-split handled via +928 chunks = 16*58)
    int lo[7];
    #pragma unroll
    for (int ni = 0; ni < 7; ++ni) {
        int c  = ni * 16 + r;
        int hr = (c >= 56) ? 1 : 0;
        lo[ni] = hr * (16 * 58) + (c - hr * 56);
    }

    f32x4 acc[4][7];
    #pragma unroll
    for (int mi = 0; mi < 4; ++mi)
        #pragma unroll
        for (int ni = 0; ni < 7; ++ni)
            #pragma unroll
            for (int v = 0; v < 4; ++v) acc[mi][ni][v] = 0.f;

    #pragma unroll
    for (int t = 0; t < 9; ++t) {
        const int kh = t / 3, kw = t - 3 * (t / 3);
        #pragma unroll
        for (int cc = 0; cc < 4; ++cc) {
            const int s = t * 4 + cc;

            // slice s landed (2 newest slices may remain in flight)
            asm volatile("s_waitcnt vmcnt(4)" ::: "memory");
            __builtin_amdgcn_sched_barrier(0);
            __builtin_amdgcn_s_barrier();           // RAW barrier - no drain
            __builtin_amdgcn_sched_barrier(0);

            if (s < 33) STAGE_A((s + 3) & 3, s + 3);   // slot (s-1)&3, now free

            const int gc = cc * 4 + g;
            const int bb = (((wn * 2 + kh) * 16 + gc) * 58 + kw);

            short8 a[4];
            #pragma unroll
            for (int mi = 0; mi < 4; ++mi)
                a[mi] = *(const short8*)
                    &ldsA[s & 3][(size_t)(((wm * 4 + mi) * 64 + lane)) * 8];

            short8 b[7];
            #pragma unroll
            for (int ni = 0; ni < 7; ++ni)
                b[ni] = *(const short8*)&ldsB[(size_t)(bb + lo[ni]) * 8];

            __builtin_amdgcn_s_setprio(1);
            #pragma unroll
            for (int mi = 0; mi < 4; ++mi)
                #pragma unroll
                for (int ni = 0; ni < 7; ++ni)
                    acc[mi][ni] = __builtin_amdgcn_mfma_f32_16x16x32_bf16(
                        a[mi], b[ni], acc[mi][ni], 0, 0, 0);
            __builtin_amdgcn_s_setprio(0);
        }
    }

    // ---- epilogue: D col = r (spatial), row = g*4+v (Cout within frag) ----
    #pragma unroll
    for (int mi = 0; mi < 4; ++mi) {
        const int o0 = wm * 64 + mi * 16 + 4 * g;
        const float4 bv = *(const float4*)&bias[o0];
        #pragma unroll
        for (int ni = 0; ni < 7; ++ni) {
            const int c  = ni * 16 + r;
            const int hr = (c >= 56) ? 1 : 0;
            const int h  = h0 + wn * 2 + hr;
            const int w  = c - hr * 56;
            #pragma unroll
            for (int v = 0; v < 4; ++v) {
                out[((size_t)(n * COUT + o0 + v) * HH + h) * WW + w] =
                    acc[mi][ni][v] + ((const float*)&bv)[v];
            }
        }
    }
}

extern "C" void kernel_launch(void* const* d_in, const int* in_sizes, int n_in,
                              void* d_out, int out_size, void* d_ws, size_t ws_size,
                              hipStream_t stream) {
    const float* x  = (const float*)d_in[0];   // (32,128,56,56)
    const float* wk = (const float*)d_in[1];   // (256,128,3,3)
    const float* b  = (const float*)d_in[2];   // (256,)
    float* out = (float*)d_out;

    unsigned short* wt2 = (unsigned short*)d_ws;   // 294,912 elems = 590 KB

    wpose_kernel<<<(36 * 16 * 64 * 8 + 255) / 256, 256, 0, stream>>>(wk, wt2);
    dim3 gc(14, NB);
    conv_mfma_kernel<<<gc, 512, 0, stream>>>(x, wt2, b, out);
    (void)ws_size; (void)in_sizes; (void)n_in; (void)out_size;
}

// Round 10
// 91.676 us; speedup vs baseline: 2.4585x; 1.2211x over previous
//
#include <hip/hip_runtime.h>
#include <hip/hip_bf16.h>

#define NB   32
#define CIN  128
#define COUT 256
#define HH   56
#define WW   56
#define CH   59        // padded B-row length in 16B chunks (944 = 16*59)

typedef __attribute__((ext_vector_type(8))) short short8;   // 8 bf16 (4 VGPRs)
typedef __attribute__((ext_vector_type(4))) float f32x4;    // MFMA accumulator

// round-to-nearest-even fp32 -> bf16 (raw u16)
__device__ __forceinline__ unsigned short f2bf(float f) {
    unsigned int u = __builtin_bit_cast(unsigned int, f);
    u = u + 0x7fffu + ((u >> 16) & 1u);
    return (unsigned short)(u >> 16);
}

// ---------------------------------------------------------------------------
// Pre-pass: weights OIHW f32 -> wt2 in EXACT MFMA A-fragment order:
//   chunk ((s*16 + f)*64 + lane), elem j:  w[o=f*16+r][c=cc*32+g*8+j][tap t]
//   (s = K-step: t = s>>2, cc = s&3;  lane: g = lane>>4, r = lane&15)
// A wave's per-step fragment load is ONE coalesced global_load_dwordx4,
// L1/L2-resident (576 KB total, same stream for every block).
// ---------------------------------------------------------------------------
__global__ __launch_bounds__(256) void wpose_kernel(const float* __restrict__ w,
                                                    unsigned short* __restrict__ wt2) {
    int q = blockIdx.x * 256 + threadIdx.x;
    if (q >= 36 * 16 * 64 * 8) return;
    int j = q & 7;
    int l = (q >> 3) & 63;
    int f = (q >> 9) & 15;
    int s = q >> 13;
    int g = l >> 4, r = l & 15;
    int t = s >> 2, cc = s & 3;
    int o = f * 16 + r;
    int c = cc * 32 + g * 8 + j;
    wt2[q] = f2bf(w[((size_t)o * CIN + c) * 9 + t]);
}

// ---------------------------------------------------------------------------
// Main conv: block = 256 Cout x 224 spatial (4 output rows h0..h0+3),
// 512 threads = 8 waves as 4(M) x 2(N); wave = 64 Cout x 112 cols
// (4 M-frags x 7 N-frags of 16x16x32; zero N-padding waste). 36 K-steps.
//
// BARRIER-FREE K-loop (r5 structure, the measured best) + explicit
// distance-1 software pipeline: alternating static register sets A0/B0,
// A1/B1 — step s+1's 4 global + 7 LDS loads issue before step s's 28 MFMAs
// (load latency ~<225 cyc fits in the ~272 cyc/SIMD MFMA window).
//   A: direct global fragment loads from wt2 (L1/L2-resident).
//   B: x rows h0-1..h0+4 transposed in-block NCHW f32 -> bf16 LDS once:
//      chunk (row*16+gc)*59 + wpos, 8 ch each; wpos 0/57/58 + OOB rows = 0.
//      CH=59: transpose writes 2-way (free), all K-loop B addressing is a
//      16-bit ds_read immediate (kh*15104 + cc*3776 + kw*16, max 41568).
// ---------------------------------------------------------------------------
__global__ __launch_bounds__(512) void conv_mfma_kernel(
        const float* __restrict__ x,
        const unsigned short* __restrict__ wt2,
        const float* __restrict__ bias,
        float* __restrict__ out) {
    __shared__ unsigned short ldsB[6 * 16 * CH * 8];    // 90624 B

    const int tid  = threadIdx.x;
    const int h0   = blockIdx.x * 4, n = blockIdx.y;
    const int wid  = tid >> 6, lane = tid & 63;
    const int wm   = wid >> 1, wn = wid & 1;            // 4M x 2N wave grid
    const int g    = lane >> 4, r = lane & 15;

    // ---- zero all chunks (pads + OOB rows stay zero) ----
    for (int i = tid; i < 6 * 16 * CH; i += 512) {
        uint4 z = {0u, 0u, 0u, 0u};
        *(uint4*)&ldsB[(size_t)i * 8] = z;
    }
    __syncthreads();

    // ---- fused transpose: lane = (wp 0..15, e 0..3).  Reads: 16 consecutive
    //      w per e-group (coalesced 64B runs). Writes: dword idx
    //      ((row*16+gc)*59 + wpos)*4 + e -> banks 4*wp+e = all 32, 2-way free.
    {
        const float* xn = x + (size_t)n * CIN * HH * WW;
        const int wp = lane & 15, e = lane >> 4;
        #pragma unroll 4
        for (int u = wid; u < 6 * 16 * 4; u += 8) {
            int wblk = u & 3;
            int gc   = (u >> 2) & 15;
            int row  = u >> 6;                  // 0..5 -> input row h0+row-1
            int hs   = h0 + row - 1;
            int wpos = wblk * 16 + wp + 1;
            if ((unsigned)hs < HH && wpos <= 56) {
                const float* p = xn + ((size_t)(gc * 8 + 2 * e) * HH + hs) * WW
                               + (wpos - 1);
                unsigned int pk = (unsigned int)f2bf(p[0])
                                | ((unsigned int)f2bf(p[HH * WW]) << 16);
                ((unsigned int*)ldsB)[((row * 16 + gc) * CH + wpos) * 4 + e] = pk;
            }
        }
    }
    __syncthreads();    // B ready; the only barriers are behind us

    // per-lane B base pointers for the 7 N-fragments
    // chunk = (wn*32 + g)*59 + lo[ni];  per-step byte offset is an immediate
    const unsigned short* bbase[7];
    #pragma unroll
    for (int ni = 0; ni < 7; ++ni) {
        int c  = ni * 16 + r;
        int hr = (c >= 56) ? 1 : 0;
        int lo = hr * (16 * CH) + (c - hr * 56);
        bbase[ni] = &ldsB[(size_t)((wn * 32 + g) * CH + lo) * 8];
    }

    f32x4 acc[4][7];
    #pragma unroll
    for (int mi = 0; mi < 4; ++mi)
        #pragma unroll
        for (int ni = 0; ni < 7; ++ni)
            #pragma unroll
            for (int v = 0; v < 4; ++v) acc[mi][ni][v] = 0.f;

    // wave's A base: fragment f = wm*4 + mi, chunk ((s*16+f)*64 + lane)
    const short8* abase = (const short8*)wt2 + (size_t)(wm * 4) * 64 + lane;

    short8 A0[4], A1[4], B0[7], B1[7];

    #define LOAD_A(dst, s)                                                      \
        _Pragma("unroll")                                                       \
        for (int mi = 0; mi < 4; ++mi)                                          \
            dst[mi] = abase[(s) * 1024 + mi * 64];

    #define LOAD_B(dst, s)                                                      \
        {                                                                       \
            const int t_ = (s) >> 2, cc_ = (s) & 3;                             \
            const int kh_ = t_ / 3, kw_ = t_ - 3 * (t_ / 3);                    \
            const int boff_ = kh_ * 15104 + cc_ * 3776 + kw_ * 16;              \
            _Pragma("unroll")                                                   \
            for (int ni = 0; ni < 7; ++ni)                                      \
                dst[ni] = *(const short8*)((const char*)bbase[ni] + boff_);     \
        }

    #define DO_MFMA(A_, B_)                                                     \
        __builtin_amdgcn_s_setprio(1);                                          \
        _Pragma("unroll")                                                       \
        for (int mi = 0; mi < 4; ++mi)                                          \
            _Pragma("unroll")                                                   \
            for (int ni = 0; ni < 7; ++ni)                                      \
                acc[mi][ni] = __builtin_amdgcn_mfma_f32_16x16x32_bf16(          \
                    A_[mi], B_[ni], acc[mi][ni], 0, 0, 0);                      \
        __builtin_amdgcn_s_setprio(0);

    LOAD_A(A0, 0)
    LOAD_B(B0, 0)

    #pragma unroll
    for (int sp = 0; sp < 18; ++sp) {
        const int s1 = 2 * sp + 1;
        // issue step s1 loads, then run step s1-1 MFMAs
        LOAD_A(A1, s1)
        LOAD_B(B1, s1)
        DO_MFMA(A0, B0)
        if (s1 + 1 <= 35) {
            LOAD_A(A0, s1 + 1)
            LOAD_B(B0, s1 + 1)
        }
        DO_MFMA(A1, B1)
    }

    // ---- epilogue: D col = r (spatial), row = g*4+v (Cout within frag) ----
    #pragma unroll
    for (int mi = 0; mi < 4; ++mi) {
        const int o0 = wm * 64 + mi * 16 + 4 * g;
        const float4 bv = *(const float4*)&bias[o0];
        #pragma unroll
        for (int ni = 0; ni < 7; ++ni) {
            const int c  = ni * 16 + r;
            const int hr = (c >= 56) ? 1 : 0;
            const int h  = h0 + wn * 2 + hr;
            const int w  = c - hr * 56;
            #pragma unroll
            for (int v = 0; v < 4; ++v) {
                out[((size_t)(n * COUT + o0 + v) * HH + h) * WW + w] =
                    acc[mi][ni][v] + ((const float*)&bv)[v];
            }
        }
    }
}

extern "C" void kernel_launch(void* const* d_in, const int* in_sizes, int n_in,
                              void* d_out, int out_size, void* d_ws, size_t ws_size,
                              hipStream_t stream) {
    const float* x  = (const float*)d_in[0];   // (32,128,56,56)
    const float* wk = (const float*)d_in[1];   // (256,128,3,3)
    const float* b  = (const float*)d_in[2];   // (256,)
    float* out = (float*)d_out;

    unsigned short* wt2 = (unsigned short*)d_ws;   // 294,912 elems = 590 KB

    wpose_kernel<<<(36 * 16 * 64 * 8 + 255) / 256, 256, 0, stream>>>(wk, wt2);
    dim3 gc(14, NB);
    conv_mfma_kernel<<<gc, 512, 0, stream>>>(x, wt2, b, out);
    (void)ws_size; (void)in_sizes; (void)n_in; (void)out_size;
}